// Round 1
// baseline (399.158 us; speedup 1.0000x reference)
//
#include <hip/hip_runtime.h>

#define TPB 256
#define EPT 8                 // elements per thread (2 x int4), consecutive -> stable order
#define EPB (TPB * EPT)       // 2048 elements per block
#define NE 8                  // experts

typedef unsigned long long u64;

// ---------------- Pass 1: per-block histogram ----------------
__global__ __launch_bounds__(TPB) void k_hist(const int* __restrict__ idx, int M,
                                              int* __restrict__ bh) {
    const int b = blockIdx.x;
    const long gbase = (long)b * EPB + threadIdx.x * EPT;

    // packed counters: lo = bins 0-3 (4 x 16b), hi = bins 4-7
    u64 lo = 0, hi = 0;
    if (gbase + EPT <= M) {
        int4 v0 = *(const int4*)(idx + gbase);
        int4 v1 = *(const int4*)(idx + gbase + 4);
        int e[8] = {v0.x, v0.y, v0.z, v0.w, v1.x, v1.y, v1.z, v1.w};
        #pragma unroll
        for (int j = 0; j < 8; ++j) {
            u64 inc = 1ULL << ((e[j] & 3) * 16);
            if (e[j] < 4) lo += inc; else hi += inc;
        }
    } else {
        for (int j = 0; j < EPT; ++j) {
            if (gbase + j < M) {
                int e = idx[gbase + j];
                u64 inc = 1ULL << ((e & 3) * 16);
                if (e < 4) lo += inc; else hi += inc;
            }
        }
    }

    // wave butterfly reduce (fields <= 64*8 = 512, fits 16b)
    const int lane = threadIdx.x & 63;
    const int wave = threadIdx.x >> 6;
    #pragma unroll
    for (int m = 1; m < 64; m <<= 1) {
        lo += __shfl_xor(lo, m);
        hi += __shfl_xor(hi, m);
    }
    __shared__ u64 wlo[TPB / 64], whi[TPB / 64];
    if (lane == 0) { wlo[wave] = lo; whi[wave] = hi; }
    __syncthreads();
    if (threadIdx.x < NE) {
        int e = threadIdx.x;
        int f = e & 3;
        int tot = 0;
        #pragma unroll
        for (int wv = 0; wv < TPB / 64; ++wv) {
            u64 p = (e < 4) ? wlo[wv] : whi[wv];
            tot += (int)((p >> (f * 16)) & 0xFFFF);
        }
        bh[(long)b * NE + e] = tot;
    }
}

// ---------------- Pass 2: global scan over (expert, block) ----------------
// 1 block, 1024 threads: 128 threads per expert, each owns a contiguous run of blocks.
__global__ __launch_bounds__(1024) void k_scan(const int* __restrict__ bh,
                                               int* __restrict__ bhx,
                                               float* __restrict__ out_counts,
                                               int nblocks, int M) {
    const int e   = threadIdx.x >> 7;    // 0..7 (expert-major order == scan order)
    const int seg = threadIdx.x & 127;
    const int segLen = (nblocks + 127) / 128;
    const int b0 = seg * segLen;
    const int b1 = (b0 + segLen < nblocks) ? (b0 + segLen) : nblocks;

    int sum = 0;
    for (int b = b0; b < b1; ++b) sum += bh[(long)b * NE + e];

    // block exclusive scan over 1024 values in threadIdx order
    const int lane = threadIdx.x & 63;
    const int wave = threadIdx.x >> 6;    // 16 waves
    int inc = sum;
    #pragma unroll
    for (int d = 1; d < 64; d <<= 1) {
        int p = __shfl_up(inc, d);
        if (lane >= d) inc += p;
    }
    __shared__ int wsum[16];
    if (lane == 63) wsum[wave] = inc;
    __syncthreads();
    int add = 0;
    for (int wv = 0; wv < wave; ++wv) add += wsum[wv];
    const int excl = inc - sum + add;    // global start for (e, seg), expert base included

    // phase 2: per-block exclusive offsets for this expert
    int run = excl;
    for (int b = b0; b < b1; ++b) {
        bhx[(long)b * NE + e] = run;
        run += bh[(long)b * NE + e];
    }

    // expert counts: difference of segment-0 starts
    __shared__ int ebase[NE + 1];
    if (seg == 0) ebase[e] = excl;
    if (threadIdx.x == 0) ebase[NE] = M;
    __syncthreads();
    if (threadIdx.x < NE)
        out_counts[threadIdx.x] = (float)(ebase[threadIdx.x + 1] - ebase[threadIdx.x]);
}

// ---------------- Pass 3: stable scatter ----------------
__global__ __launch_bounds__(TPB) void k_scatter(const int* __restrict__ idx,
                                                 const float* __restrict__ scores,
                                                 int M,
                                                 const int* __restrict__ bhx,
                                                 float* __restrict__ outS,
                                                 float* __restrict__ outT) {
    const int b = blockIdx.x;
    const int t = threadIdx.x;
    const long gbase = (long)b * EPB + t * EPT;

    __shared__ int sOff[NE];
    if (t < NE) sOff[t] = bhx[(long)b * NE + t];

    int  e[EPT];
    float s[EPT];
    int  nval = 0;
    const bool full = (gbase + EPT <= M);
    if (full) {
        int4  v0 = *(const int4*)(idx + gbase);
        int4  v1 = *(const int4*)(idx + gbase + 4);
        float4 s0 = *(const float4*)(scores + gbase);
        float4 s1 = *(const float4*)(scores + gbase + 4);
        e[0]=v0.x; e[1]=v0.y; e[2]=v0.z; e[3]=v0.w;
        e[4]=v1.x; e[5]=v1.y; e[6]=v1.z; e[7]=v1.w;
        s[0]=s0.x; s[1]=s0.y; s[2]=s0.z; s[3]=s0.w;
        s[4]=s1.x; s[5]=s1.y; s[6]=s1.z; s[7]=s1.w;
        nval = EPT;
    } else {
        for (int j = 0; j < EPT; ++j) {
            if (gbase + j < M) { e[j] = idx[gbase + j]; s[j] = scores[gbase + j]; ++nval; }
            else { e[j] = 0; s[j] = 0.f; }
        }
    }

    // packed per-thread counts (in element order)
    u64 lo = 0, hi = 0;
    for (int j = 0; j < nval; ++j) {
        u64 inc = 1ULL << ((e[j] & 3) * 16);
        if (e[j] < 4) lo += inc; else hi += inc;
    }

    // block exclusive scan of packed counters (fields <= 2048, fits 16b)
    const int lane = threadIdx.x & 63;
    const int wave = threadIdx.x >> 6;
    u64 il = lo, ih = hi;
    #pragma unroll
    for (int d = 1; d < 64; d <<= 1) {
        u64 pl = __shfl_up(il, (unsigned)d);
        u64 ph = __shfl_up(ih, (unsigned)d);
        if (lane >= d) { il += pl; ih += ph; }
    }
    __shared__ u64 wlo[TPB / 64], whi[TPB / 64];
    if (lane == 63) { wlo[wave] = il; whi[wave] = ih; }
    __syncthreads();
    u64 addl = 0, addh = 0;
    for (int wv = 0; wv < wave; ++wv) { addl += wlo[wv]; addh += whi[wv]; }
    u64 rl = il - lo + addl;   // running exclusive packed offsets
    u64 rh = ih - hi + addh;

    for (int j = 0; j < nval; ++j) {
        const int ej = e[j];
        const int f  = ej & 3;
        const u64 inc = 1ULL << (f * 16);
        int off;
        if (ej < 4) { off = (int)((rl >> (f * 16)) & 0xFFFF); rl += inc; }
        else        { off = (int)((rh >> (f * 16)) & 0xFFFF); rh += inc; }
        const int pos = sOff[ej] + off;
        outS[pos] = s[j];
        outT[pos] = (float)(int)((gbase + j) >> 1);   // order // TOP_K (TOP_K == 2)
    }
}

extern "C" void kernel_launch(void* const* d_in, const int* in_sizes, int n_in,
                              void* d_out, int out_size, void* d_ws, size_t ws_size,
                              hipStream_t stream) {
    const float* scores = (const float*)d_in[0];
    const int*   idx    = (const int*)d_in[1];
    const int M = in_sizes[1];                 // N_TOKENS * TOP_K flat keys

    float* out  = (float*)d_out;
    float* outS = out;                          // [0, M)   sorted scores
    float* outT = out + M;                      // [M, 2M)  token indices (as f32, exact < 2^24)
    float* outC = out + 2 * (long)M;            // [2M, 2M+8) expert counts

    const int nblocks = (M + EPB - 1) / EPB;    // 8192 for M = 16,777,216
    int* bh  = (int*)d_ws;                      // nblocks * 8 ints
    int* bhx = bh + (long)nblocks * NE;         // nblocks * 8 ints

    k_hist   <<<nblocks, TPB, 0, stream>>>(idx, M, bh);
    k_scan   <<<1, 1024, 0, stream>>>(bh, bhx, outC, nblocks, M);
    k_scatter<<<nblocks, TPB, 0, stream>>>(idx, scores, M, bhx, outS, outT);
}

// Round 2
// 290.709 us; speedup vs baseline: 1.3731x; 1.3731x over previous
//
#include <hip/hip_runtime.h>

#define TPB 256
#define EPT 8                 // elements per thread (2 x int4), consecutive -> stable order
#define EPB (TPB * EPT)       // 2048 elements per block
#define NE 8                  // experts

typedef unsigned long long u64;

// ---------------- Pass 1: per-block histogram (expert-major output) ----------------
__global__ __launch_bounds__(TPB) void k_hist(const int* __restrict__ idx, int M,
                                              int* __restrict__ bh, int nblocks) {
    const int b = blockIdx.x;
    const long gbase = (long)b * EPB + threadIdx.x * EPT;

    // packed counters: lo = bins 0-3 (4 x 16b), hi = bins 4-7
    u64 lo = 0, hi = 0;
    if (gbase + EPT <= M) {
        int4 v0 = *(const int4*)(idx + gbase);
        int4 v1 = *(const int4*)(idx + gbase + 4);
        int e[8] = {v0.x, v0.y, v0.z, v0.w, v1.x, v1.y, v1.z, v1.w};
        #pragma unroll
        for (int j = 0; j < 8; ++j) {
            u64 inc = 1ULL << ((e[j] & 3) * 16);
            if (e[j] < 4) lo += inc; else hi += inc;
        }
    } else {
        for (int j = 0; j < EPT; ++j) {
            if (gbase + j < M) {
                int e = idx[gbase + j];
                u64 inc = 1ULL << ((e & 3) * 16);
                if (e < 4) lo += inc; else hi += inc;
            }
        }
    }

    // wave butterfly reduce (fields <= 64*8 = 512, fits 16b)
    const int lane = threadIdx.x & 63;
    const int wave = threadIdx.x >> 6;
    #pragma unroll
    for (int m = 1; m < 64; m <<= 1) {
        lo += __shfl_xor(lo, m);
        hi += __shfl_xor(hi, m);
    }
    __shared__ u64 wlo[TPB / 64], whi[TPB / 64];
    if (lane == 0) { wlo[wave] = lo; whi[wave] = hi; }
    __syncthreads();
    if (threadIdx.x < NE) {
        int e = threadIdx.x;
        int f = e & 3;
        int tot = 0;
        #pragma unroll
        for (int wv = 0; wv < TPB / 64; ++wv) {
            u64 p = (e < 4) ? wlo[wv] : whi[wv];
            tot += (int)((p >> (f * 16)) & 0xFFFF);
        }
        bh[(long)e * nblocks + b] = tot;   // expert-major: flat array is in scan order
    }
}

// ---------------- Pass 2: single-block scan over flat (expert-major) array ----------------
// bh flat layout IS the scan order. 1024 threads, contiguous per-thread segments, int4 I/O.
__global__ __launch_bounds__(1024) void k_scan(const int* __restrict__ bh,
                                               int* __restrict__ bhx,
                                               float* __restrict__ out_counts,
                                               int nblocks, int M) {
    const int N = nblocks * NE;
    const int L = (N + 1023) >> 10;          // per-thread segment length
    const int p0 = threadIdx.x * L;
    const int p1 = (p0 + L < N) ? (p0 + L) : N;
    const bool vec = ((L & 3) == 0) && (p0 + L <= N);

    // phase 1: per-thread segment sum
    int sum = 0;
    if (vec) {
        for (int i = 0; i < L; i += 4) {
            int4 v = *(const int4*)(bh + p0 + i);
            sum += v.x + v.y + v.z + v.w;
        }
    } else {
        for (int p = p0; p < p1; ++p) sum += bh[p];
    }

    // block exclusive scan over 1024 sums
    const int lane = threadIdx.x & 63;
    const int wave = threadIdx.x >> 6;    // 16 waves
    int inc = sum;
    #pragma unroll
    for (int d = 1; d < 64; d <<= 1) {
        int p = __shfl_up(inc, d);
        if (lane >= d) inc += p;
    }
    __shared__ int wsum[16];
    if (lane == 63) wsum[wave] = inc;
    __syncthreads();
    int add = 0;
    for (int wv = 0; wv < wave; ++wv) add += wsum[wv];
    int run = inc - sum + add;            // exclusive prefix at p0

    // phase 2: write running exclusive prefix
    if (vec) {
        for (int i = 0; i < L; i += 4) {
            int4 v = *(const int4*)(bh + p0 + i);
            int4 w;
            w.x = run; run += v.x;
            w.y = run; run += v.y;
            w.z = run; run += v.z;
            w.w = run; run += v.w;
            *(int4*)(bhx + p0 + i) = w;
        }
    } else {
        for (int p = p0; p < p1; ++p) { bhx[p] = run; run += bh[p]; }
    }

    // expert counts: bhx[e*nblocks] is expert e's global base
    __threadfence_block();
    __syncthreads();
    __shared__ int ebase[NE + 1];
    if (threadIdx.x < NE) ebase[threadIdx.x] = bhx[(long)threadIdx.x * nblocks];
    if (threadIdx.x == 0) ebase[NE] = M;
    __syncthreads();
    if (threadIdx.x < NE)
        out_counts[threadIdx.x] = (float)(ebase[threadIdx.x + 1] - ebase[threadIdx.x]);
}

// ---------------- Pass 3: stable scatter, LDS-staged for coalesced output ----------------
__global__ __launch_bounds__(TPB) void k_scatter(const int* __restrict__ idx,
                                                 const float* __restrict__ scores,
                                                 int M,
                                                 const int* __restrict__ bhx, int nblocks,
                                                 float* __restrict__ outS,
                                                 float* __restrict__ outT) {
    const int b = blockIdx.x;
    const int t = threadIdx.x;
    const long gbase = (long)b * EPB + t * EPT;

    __shared__ int sOff[NE];
    if (t < NE) sOff[t] = bhx[(long)t * nblocks + b];

    int  e[EPT];
    float s[EPT];
    int  nval = 0;
    if (gbase + EPT <= M) {
        int4  v0 = *(const int4*)(idx + gbase);
        int4  v1 = *(const int4*)(idx + gbase + 4);
        float4 s0 = *(const float4*)(scores + gbase);
        float4 s1 = *(const float4*)(scores + gbase + 4);
        e[0]=v0.x; e[1]=v0.y; e[2]=v0.z; e[3]=v0.w;
        e[4]=v1.x; e[5]=v1.y; e[6]=v1.z; e[7]=v1.w;
        s[0]=s0.x; s[1]=s0.y; s[2]=s0.z; s[3]=s0.w;
        s[4]=s1.x; s[5]=s1.y; s[6]=s1.z; s[7]=s1.w;
        nval = EPT;
    } else {
        for (int j = 0; j < EPT; ++j) {
            if (gbase + j < M) { e[j] = idx[gbase + j]; s[j] = scores[gbase + j]; ++nval; }
            else { e[j] = 0; s[j] = 0.f; }
        }
    }

    // packed per-thread counts (element order)
    u64 lo = 0, hi = 0;
    for (int j = 0; j < nval; ++j) {
        u64 inc = 1ULL << ((e[j] & 3) * 16);
        if (e[j] < 4) lo += inc; else hi += inc;
    }

    // block exclusive scan of packed counters (fields <= 2048, fits 16b)
    const int lane = t & 63;
    const int wave = t >> 6;
    u64 il = lo, ih = hi;
    #pragma unroll
    for (int d = 1; d < 64; d <<= 1) {
        u64 pl = __shfl_up(il, (unsigned)d);
        u64 ph = __shfl_up(ih, (unsigned)d);
        if (lane >= d) { il += pl; ih += ph; }
    }
    __shared__ u64 wlo[TPB / 64], whi[TPB / 64];
    if (lane == 63) { wlo[wave] = il; whi[wave] = ih; }
    __syncthreads();
    u64 addl = 0, addh = 0;
    for (int wv = 0; wv < wave; ++wv) { addl += wlo[wv]; addh += whi[wv]; }
    u64 rl = il - lo + addl;   // running exclusive packed offsets
    u64 rh = ih - hi + addh;

    // block totals -> per-expert local bases (wave-uniform scalar compute)
    const u64 tl = wlo[0] + wlo[1] + wlo[2] + wlo[3];
    const u64 th = whi[0] + whi[1] + whi[2] + whi[3];
    int cnt[NE], lBase[NE];
    {
        #pragma unroll
        for (int k = 0; k < 4; ++k) cnt[k]     = (int)((tl >> (16 * k)) & 0xFFFF);
        #pragma unroll
        for (int k = 0; k < 4; ++k) cnt[4 + k] = (int)((th >> (16 * k)) & 0xFFFF);
        int runb = 0;
        #pragma unroll
        for (int k = 0; k < NE; ++k) { lBase[k] = runb; runb += cnt[k]; }
    }

    // stage into LDS in final (sorted) order
    __shared__ float lsS[EPB];
    __shared__ float lsT[EPB];
    for (int j = 0; j < nval; ++j) {
        const int ej = e[j];
        const int f  = ej & 3;
        const u64 inc = 1ULL << (f * 16);
        int off;
        if (ej < 4) { off = (int)((rl >> (f * 16)) & 0xFFFF); rl += inc; }
        else        { off = (int)((rh >> (f * 16)) & 0xFFFF); rh += inc; }
        const int p = lBase[ej] + off;
        lsS[p] = s[j];
        lsT[p] = (float)(int)((gbase + j) >> 1);   // order // TOP_K (TOP_K == 2)
    }
    __syncthreads();

    // coalesced copy out: per expert, contiguous run
    #pragma unroll
    for (int k = 0; k < NE; ++k) {
        const int c  = cnt[k];
        const int g0 = sOff[k];
        const int l0 = lBase[k];
        for (int i = t; i < c; i += TPB) {
            outS[g0 + i] = lsS[l0 + i];
            outT[g0 + i] = lsT[l0 + i];
        }
    }
}

extern "C" void kernel_launch(void* const* d_in, const int* in_sizes, int n_in,
                              void* d_out, int out_size, void* d_ws, size_t ws_size,
                              hipStream_t stream) {
    const float* scores = (const float*)d_in[0];
    const int*   idx    = (const int*)d_in[1];
    const int M = in_sizes[1];                 // N_TOKENS * TOP_K flat keys

    float* out  = (float*)d_out;
    float* outS = out;                          // [0, M)   sorted scores
    float* outT = out + M;                      // [M, 2M)  token indices (as f32, exact < 2^24)
    float* outC = out + 2 * (long)M;            // [2M, 2M+8) expert counts

    const int nblocks = (M + EPB - 1) / EPB;    // 8192 for M = 16,777,216
    int* bh  = (int*)d_ws;                      // NE * nblocks ints, expert-major
    int* bhx = bh + (long)NE * nblocks;         // NE * nblocks ints, expert-major

    k_hist   <<<nblocks, TPB, 0, stream>>>(idx, M, bh, nblocks);
    k_scan   <<<1, 1024, 0, stream>>>(bh, bhx, outC, nblocks, M);
    k_scatter<<<nblocks, TPB, 0, stream>>>(idx, scores, M, bhx, nblocks, outS, outT);
}

// Round 3
// 264.926 us; speedup vs baseline: 1.5067x; 1.0973x over previous
//
#include <hip/hip_runtime.h>

#define TPB 512
#define EPT 8                 // elements per thread (2 x int4), consecutive -> stable order
#define EPB (TPB * EPT)       // 4096 elements per block
#define NE 8                  // experts
#define NWAVE (TPB / 64)      // 8 waves

typedef unsigned long long u64;
typedef int   v4i __attribute__((ext_vector_type(4)));
typedef float v4f __attribute__((ext_vector_type(4)));

// ---------------- Pass 1: per-block histogram (expert-major output) ----------------
__global__ __launch_bounds__(TPB) void k_hist(const int* __restrict__ idx, int M,
                                              int* __restrict__ bh, int nblocks) {
    const int b = blockIdx.x;
    const long gbase = (long)b * EPB + threadIdx.x * EPT;

    // packed counters: lo = bins 0-3 (4 x 16b), hi = bins 4-7
    u64 lo = 0, hi = 0;
    if (gbase + EPT <= M) {
        v4i v0 = __builtin_nontemporal_load((const v4i*)(idx + gbase));
        v4i v1 = __builtin_nontemporal_load((const v4i*)(idx + gbase + 4));
        int e[8] = {v0.x, v0.y, v0.z, v0.w, v1.x, v1.y, v1.z, v1.w};
        #pragma unroll
        for (int j = 0; j < 8; ++j) {
            u64 inc = 1ULL << ((e[j] & 3) * 16);
            if (e[j] < 4) lo += inc; else hi += inc;
        }
    } else {
        for (int j = 0; j < EPT; ++j) {
            if (gbase + j < M) {
                int e = idx[gbase + j];
                u64 inc = 1ULL << ((e & 3) * 16);
                if (e < 4) lo += inc; else hi += inc;
            }
        }
    }

    // wave butterfly reduce (fields <= 64*8 = 512, fits 16b)
    const int lane = threadIdx.x & 63;
    const int wave = threadIdx.x >> 6;
    #pragma unroll
    for (int m = 1; m < 64; m <<= 1) {
        lo += __shfl_xor(lo, m);
        hi += __shfl_xor(hi, m);
    }
    __shared__ u64 wlo[NWAVE], whi[NWAVE];
    if (lane == 0) { wlo[wave] = lo; whi[wave] = hi; }
    __syncthreads();
    if (threadIdx.x < NE) {
        int e = threadIdx.x;
        int f = e & 3;
        int tot = 0;
        #pragma unroll
        for (int wv = 0; wv < NWAVE; ++wv) {
            u64 p = (e < 4) ? wlo[wv] : whi[wv];
            tot += (int)((p >> (f * 16)) & 0xFFFF);
        }
        bh[(long)e * nblocks + b] = tot;   // expert-major: flat array is in scan order
    }
}

// ---------------- Pass 2: single-block scan over flat (expert-major) array ----------------
__global__ __launch_bounds__(1024) void k_scan(const int* __restrict__ bh,
                                               int* __restrict__ bhx,
                                               float* __restrict__ out_counts,
                                               int nblocks, int M) {
    const int N = nblocks * NE;
    const int L = (N + 1023) >> 10;          // per-thread segment length
    const int p0 = threadIdx.x * L;
    const int p1 = (p0 + L < N) ? (p0 + L) : N;
    const bool vec = ((L & 3) == 0) && (p0 + L <= N);

    // phase 1: per-thread segment sum
    int sum = 0;
    if (vec) {
        for (int i = 0; i < L; i += 4) {
            int4 v = *(const int4*)(bh + p0 + i);
            sum += v.x + v.y + v.z + v.w;
        }
    } else {
        for (int p = p0; p < p1; ++p) sum += bh[p];
    }

    // block exclusive scan over 1024 sums
    const int lane = threadIdx.x & 63;
    const int wave = threadIdx.x >> 6;    // 16 waves
    int inc = sum;
    #pragma unroll
    for (int d = 1; d < 64; d <<= 1) {
        int p = __shfl_up(inc, d);
        if (lane >= d) inc += p;
    }
    __shared__ int wsum[16];
    if (lane == 63) wsum[wave] = inc;
    __syncthreads();
    int add = 0;
    for (int wv = 0; wv < wave; ++wv) add += wsum[wv];
    int run = inc - sum + add;            // exclusive prefix at p0

    // phase 2: write running exclusive prefix
    if (vec) {
        for (int i = 0; i < L; i += 4) {
            int4 v = *(const int4*)(bh + p0 + i);
            int4 w;
            w.x = run; run += v.x;
            w.y = run; run += v.y;
            w.z = run; run += v.z;
            w.w = run; run += v.w;
            *(int4*)(bhx + p0 + i) = w;
        }
    } else {
        for (int p = p0; p < p1; ++p) { bhx[p] = run; run += bh[p]; }
    }

    // expert counts: bhx[e*nblocks] is expert e's global base
    __threadfence_block();
    __syncthreads();
    __shared__ int ebase[NE + 1];
    if (threadIdx.x < NE) ebase[threadIdx.x] = bhx[(long)threadIdx.x * nblocks];
    if (threadIdx.x == 0) ebase[NE] = M;
    __syncthreads();
    if (threadIdx.x < NE)
        out_counts[threadIdx.x] = (float)(ebase[threadIdx.x + 1] - ebase[threadIdx.x]);
}

// ---------------- Pass 3: stable scatter, LDS-staged for coalesced output ----------------
__global__ __launch_bounds__(TPB) void k_scatter(const int* __restrict__ idx,
                                                 const float* __restrict__ scores,
                                                 int M,
                                                 const int* __restrict__ bhx, int nblocks,
                                                 float* __restrict__ outS,
                                                 float* __restrict__ outT) {
    const int b = blockIdx.x;
    const int t = threadIdx.x;
    const long gbase = (long)b * EPB + t * EPT;

    __shared__ int sOff[NE];
    if (t < NE) sOff[t] = bhx[(long)t * nblocks + b];

    int  e[EPT];
    float s[EPT];
    int  nval = 0;
    if (gbase + EPT <= M) {
        v4i v0 = __builtin_nontemporal_load((const v4i*)(idx + gbase));
        v4i v1 = __builtin_nontemporal_load((const v4i*)(idx + gbase + 4));
        v4f s0 = __builtin_nontemporal_load((const v4f*)(scores + gbase));
        v4f s1 = __builtin_nontemporal_load((const v4f*)(scores + gbase + 4));
        e[0]=v0.x; e[1]=v0.y; e[2]=v0.z; e[3]=v0.w;
        e[4]=v1.x; e[5]=v1.y; e[6]=v1.z; e[7]=v1.w;
        s[0]=s0.x; s[1]=s0.y; s[2]=s0.z; s[3]=s0.w;
        s[4]=s1.x; s[5]=s1.y; s[6]=s1.z; s[7]=s1.w;
        nval = EPT;
    } else {
        for (int j = 0; j < EPT; ++j) {
            if (gbase + j < M) { e[j] = idx[gbase + j]; s[j] = scores[gbase + j]; ++nval; }
            else { e[j] = 0; s[j] = 0.f; }
        }
    }

    // packed per-thread counts (element order)
    u64 lo = 0, hi = 0;
    for (int j = 0; j < nval; ++j) {
        u64 inc = 1ULL << ((e[j] & 3) * 16);
        if (e[j] < 4) lo += inc; else hi += inc;
    }

    // block exclusive scan of packed counters (fields <= 4096, fits 16b)
    const int lane = t & 63;
    const int wave = t >> 6;
    u64 il = lo, ih = hi;
    #pragma unroll
    for (int d = 1; d < 64; d <<= 1) {
        u64 pl = __shfl_up(il, (unsigned)d);
        u64 ph = __shfl_up(ih, (unsigned)d);
        if (lane >= d) { il += pl; ih += ph; }
    }
    __shared__ u64 wlo[NWAVE], whi[NWAVE];
    if (lane == 63) { wlo[wave] = il; whi[wave] = ih; }
    __syncthreads();
    u64 addl = 0, addh = 0;
    for (int wv = 0; wv < wave; ++wv) { addl += wlo[wv]; addh += whi[wv]; }
    u64 rl = il - lo + addl;   // running exclusive packed offsets
    u64 rh = ih - hi + addh;

    // block totals -> per-expert local bases (wave-uniform scalar compute)
    u64 tl = 0, th = 0;
    #pragma unroll
    for (int wv = 0; wv < NWAVE; ++wv) { tl += wlo[wv]; th += whi[wv]; }
    int cnt[NE], lBase[NE];
    {
        #pragma unroll
        for (int k = 0; k < 4; ++k) cnt[k]     = (int)((tl >> (16 * k)) & 0xFFFF);
        #pragma unroll
        for (int k = 0; k < 4; ++k) cnt[4 + k] = (int)((th >> (16 * k)) & 0xFFFF);
        int runb = 0;
        #pragma unroll
        for (int k = 0; k < NE; ++k) { lBase[k] = runb; runb += cnt[k]; }
    }

    // stage into LDS in final (sorted) order
    __shared__ float lsS[EPB];
    __shared__ float lsT[EPB];
    for (int j = 0; j < nval; ++j) {
        const int ej = e[j];
        const int f  = ej & 3;
        const u64 inc = 1ULL << (f * 16);
        int off;
        if (ej < 4) { off = (int)((rl >> (f * 16)) & 0xFFFF); rl += inc; }
        else        { off = (int)((rh >> (f * 16)) & 0xFFFF); rh += inc; }
        const int p = lBase[ej] + off;
        lsS[p] = s[j];
        lsT[p] = (float)(int)((gbase + j) >> 1);   // order // TOP_K (TOP_K == 2)
    }
    __syncthreads();

    // coalesced copy out: per expert, contiguous run (nontemporal, write-once)
    #pragma unroll
    for (int k = 0; k < NE; ++k) {
        const int c  = cnt[k];
        const int g0 = sOff[k];
        const int l0 = lBase[k];
        for (int i = t; i < c; i += TPB) {
            __builtin_nontemporal_store(lsS[l0 + i], outS + g0 + i);
            __builtin_nontemporal_store(lsT[l0 + i], outT + g0 + i);
        }
    }
}

extern "C" void kernel_launch(void* const* d_in, const int* in_sizes, int n_in,
                              void* d_out, int out_size, void* d_ws, size_t ws_size,
                              hipStream_t stream) {
    const float* scores = (const float*)d_in[0];
    const int*   idx    = (const int*)d_in[1];
    const int M = in_sizes[1];                 // N_TOKENS * TOP_K flat keys

    float* out  = (float*)d_out;
    float* outS = out;                          // [0, M)   sorted scores
    float* outT = out + M;                      // [M, 2M)  token indices (as f32, exact < 2^24)
    float* outC = out + 2 * (long)M;            // [2M, 2M+8) expert counts

    const int nblocks = (M + EPB - 1) / EPB;    // 4096 for M = 16,777,216
    int* bh  = (int*)d_ws;                      // NE * nblocks ints, expert-major
    int* bhx = bh + (long)NE * nblocks;         // NE * nblocks ints, expert-major

    k_hist   <<<nblocks, TPB, 0, stream>>>(idx, M, bh, nblocks);
    k_scan   <<<1, 1024, 0, stream>>>(bh, bhx, outC, nblocks, M);
    k_scatter<<<nblocks, TPB, 0, stream>>>(idx, scores, M, bhx, nblocks, outS, outT);
}

// Round 4
// 259.802 us; speedup vs baseline: 1.5364x; 1.0197x over previous
//
#include <hip/hip_runtime.h>

#define TPB 512
#define EPT 8                 // elements per thread (2 x int4), consecutive -> stable order
#define EPB (TPB * EPT)       // 4096 elements per block
#define NE 8                  // experts
#define NWAVE (TPB / 64)      // 8 waves

typedef unsigned long long u64;
typedef unsigned int u32;
typedef int   v4i __attribute__((ext_vector_type(4)));
typedef float v4f __attribute__((ext_vector_type(4)));

// ---------------- Pass 1: histogram (expert-major) + 4-bit packed key stream ----------------
__global__ __launch_bounds__(TPB) void k_hist(const int* __restrict__ idx, int M,
                                              int* __restrict__ bh, int nblocks,
                                              u32* __restrict__ kpk) {
    const int b = blockIdx.x;
    const long gbase = (long)b * EPB + threadIdx.x * EPT;

    // packed counters: lo = bins 0-3 (4 x 16b), hi = bins 4-7
    u64 lo = 0, hi = 0;
    u32 kp = 0;
    if (gbase + EPT <= M) {
        v4i v0 = __builtin_nontemporal_load((const v4i*)(idx + gbase));
        v4i v1 = __builtin_nontemporal_load((const v4i*)(idx + gbase + 4));
        int e[8] = {v0.x, v0.y, v0.z, v0.w, v1.x, v1.y, v1.z, v1.w};
        #pragma unroll
        for (int j = 0; j < 8; ++j) {
            kp |= ((u32)(e[j] & 7)) << (4 * j);
            u64 inc = 1ULL << ((e[j] & 3) * 16);
            if (e[j] < 4) lo += inc; else hi += inc;
        }
        __builtin_nontemporal_store(kp, kpk + (long)b * TPB + threadIdx.x);
    } else if (gbase < M) {
        for (int j = 0; j < EPT; ++j) {
            if (gbase + j < M) {
                int e = idx[gbase + j];
                kp |= ((u32)(e & 7)) << (4 * j);
                u64 inc = 1ULL << ((e & 3) * 16);
                if (e < 4) lo += inc; else hi += inc;
            }
        }
        kpk[(long)b * TPB + threadIdx.x] = kp;
    }

    // wave butterfly reduce (fields <= 64*8 = 512, fits 16b)
    const int lane = threadIdx.x & 63;
    const int wave = threadIdx.x >> 6;
    #pragma unroll
    for (int m = 1; m < 64; m <<= 1) {
        lo += __shfl_xor(lo, m);
        hi += __shfl_xor(hi, m);
    }
    __shared__ u64 wlo[NWAVE], whi[NWAVE];
    if (lane == 0) { wlo[wave] = lo; whi[wave] = hi; }
    __syncthreads();
    if (threadIdx.x < NE) {
        int e = threadIdx.x;
        int f = e & 3;
        int tot = 0;
        #pragma unroll
        for (int wv = 0; wv < NWAVE; ++wv) {
            u64 p = (e < 4) ? wlo[wv] : whi[wv];
            tot += (int)((p >> (f * 16)) & 0xFFFF);
        }
        bh[(long)e * nblocks + b] = tot;   // expert-major: flat array is in scan order
    }
}

// ---------------- Pass 2: single-block scan over flat (expert-major) array ----------------
__global__ __launch_bounds__(1024) void k_scan(const int* __restrict__ bh,
                                               int* __restrict__ bhx,
                                               float* __restrict__ out_counts,
                                               int nblocks, int M) {
    const int N = nblocks * NE;
    const int L = (N + 1023) >> 10;          // per-thread segment length
    const int p0 = threadIdx.x * L;
    const int p1 = (p0 + L < N) ? (p0 + L) : N;
    const bool vec = ((L & 3) == 0) && (p0 + L <= N);

    int sum = 0;
    if (vec) {
        for (int i = 0; i < L; i += 4) {
            int4 v = *(const int4*)(bh + p0 + i);
            sum += v.x + v.y + v.z + v.w;
        }
    } else {
        for (int p = p0; p < p1; ++p) sum += bh[p];
    }

    const int lane = threadIdx.x & 63;
    const int wave = threadIdx.x >> 6;    // 16 waves
    int inc = sum;
    #pragma unroll
    for (int d = 1; d < 64; d <<= 1) {
        int p = __shfl_up(inc, d);
        if (lane >= d) inc += p;
    }
    __shared__ int wsum[16];
    if (lane == 63) wsum[wave] = inc;
    __syncthreads();
    int add = 0;
    for (int wv = 0; wv < wave; ++wv) add += wsum[wv];
    int run = inc - sum + add;            // exclusive prefix at p0

    if (vec) {
        for (int i = 0; i < L; i += 4) {
            int4 v = *(const int4*)(bh + p0 + i);
            int4 w;
            w.x = run; run += v.x;
            w.y = run; run += v.y;
            w.z = run; run += v.z;
            w.w = run; run += v.w;
            *(int4*)(bhx + p0 + i) = w;
        }
    } else {
        for (int p = p0; p < p1; ++p) { bhx[p] = run; run += bh[p]; }
    }

    __threadfence_block();
    __syncthreads();
    __shared__ int ebase[NE + 1];
    if (threadIdx.x < NE) ebase[threadIdx.x] = bhx[(long)threadIdx.x * nblocks];
    if (threadIdx.x == 0) ebase[NE] = M;
    __syncthreads();
    if (threadIdx.x < NE)
        out_counts[threadIdx.x] = (float)(ebase[threadIdx.x + 1] - ebase[threadIdx.x]);
}

// ---------------- Pass 3: stable scatter from packed keys, LDS-staged ----------------
__global__ __launch_bounds__(TPB) void k_scatter(const u32* __restrict__ kpk,
                                                 const float* __restrict__ scores,
                                                 int M,
                                                 const int* __restrict__ bhx, int nblocks,
                                                 float* __restrict__ outS,
                                                 float* __restrict__ outT) {
    const int b = blockIdx.x;
    const int t = threadIdx.x;
    const long gbase = (long)b * EPB + t * EPT;

    __shared__ int sOff[NE];
    if (t < NE) sOff[t] = bhx[(long)t * nblocks + b];

    int  e[EPT];
    float s[EPT];
    int  nval = 0;
    if (gbase + EPT <= M) {
        u32 kp = __builtin_nontemporal_load(kpk + (long)b * TPB + t);
        v4f s0 = __builtin_nontemporal_load((const v4f*)(scores + gbase));
        v4f s1 = __builtin_nontemporal_load((const v4f*)(scores + gbase + 4));
        #pragma unroll
        for (int j = 0; j < 8; ++j) e[j] = (int)((kp >> (4 * j)) & 7u);
        s[0]=s0.x; s[1]=s0.y; s[2]=s0.z; s[3]=s0.w;
        s[4]=s1.x; s[5]=s1.y; s[6]=s1.z; s[7]=s1.w;
        nval = EPT;
    } else if (gbase < M) {
        u32 kp = kpk[(long)b * TPB + t];
        for (int j = 0; j < EPT; ++j) {
            if (gbase + j < M) { e[j] = (int)((kp >> (4 * j)) & 7u); s[j] = scores[gbase + j]; ++nval; }
            else { e[j] = 0; s[j] = 0.f; }
        }
    } else {
        for (int j = 0; j < EPT; ++j) { e[j] = 0; s[j] = 0.f; }
    }

    // packed per-thread counts (element order)
    u64 lo = 0, hi = 0;
    for (int j = 0; j < nval; ++j) {
        u64 inc = 1ULL << ((e[j] & 3) * 16);
        if (e[j] < 4) lo += inc; else hi += inc;
    }

    // block exclusive scan of packed counters (fields <= 4096, fits 16b)
    const int lane = t & 63;
    const int wave = t >> 6;
    u64 il = lo, ih = hi;
    #pragma unroll
    for (int d = 1; d < 64; d <<= 1) {
        u64 pl = __shfl_up(il, (unsigned)d);
        u64 ph = __shfl_up(ih, (unsigned)d);
        if (lane >= d) { il += pl; ih += ph; }
    }
    __shared__ u64 wlo[NWAVE], whi[NWAVE];
    if (lane == 63) { wlo[wave] = il; whi[wave] = ih; }
    __syncthreads();
    u64 addl = 0, addh = 0;
    for (int wv = 0; wv < wave; ++wv) { addl += wlo[wv]; addh += whi[wv]; }
    u64 rl = il - lo + addl;   // running exclusive packed offsets
    u64 rh = ih - hi + addh;

    // block totals -> per-expert local bases
    u64 tl = 0, th = 0;
    #pragma unroll
    for (int wv = 0; wv < NWAVE; ++wv) { tl += wlo[wv]; th += whi[wv]; }
    int cnt[NE], lBase[NE];
    {
        #pragma unroll
        for (int k = 0; k < 4; ++k) cnt[k]     = (int)((tl >> (16 * k)) & 0xFFFF);
        #pragma unroll
        for (int k = 0; k < 4; ++k) cnt[4 + k] = (int)((th >> (16 * k)) & 0xFFFF);
        int runb = 0;
        #pragma unroll
        for (int k = 0; k < NE; ++k) { lBase[k] = runb; runb += cnt[k]; }
    }

    // stage into LDS in final (sorted) order
    __shared__ float lsS[EPB];
    __shared__ float lsT[EPB];
    for (int j = 0; j < nval; ++j) {
        const int ej = e[j];
        const int f  = ej & 3;
        const u64 inc = 1ULL << (f * 16);
        int off;
        if (ej < 4) { off = (int)((rl >> (f * 16)) & 0xFFFF); rl += inc; }
        else        { off = (int)((rh >> (f * 16)) & 0xFFFF); rh += inc; }
        const int p = lBase[ej] + off;
        lsS[p] = s[j];
        lsT[p] = (float)(int)((gbase + j) >> 1);   // order // TOP_K (TOP_K == 2)
    }
    __syncthreads();

    // coalesced copy out: per expert run, 16B-aligned float4 body + scalar head/tail
    #pragma unroll
    for (int k = 0; k < NE; ++k) {
        const int c  = cnt[k];
        const int g0 = sOff[k];
        const int l0 = lBase[k];
        const int head = min((4 - (g0 & 3)) & 3, c);
        const int rem  = c - head;
        const int nb   = (rem > 0) ? (rem >> 2) : 0;
        const int done = head + 4 * nb;
        const int tail = c - done;

        if (t < head) {
            __builtin_nontemporal_store(lsS[l0 + t], outS + g0 + t);
            __builtin_nontemporal_store(lsT[l0 + t], outT + g0 + t);
        }
        for (int j4 = t; j4 < nb; j4 += TPB) {
            const int i = head + 4 * j4;
            v4f vs = { lsS[l0+i], lsS[l0+i+1], lsS[l0+i+2], lsS[l0+i+3] };
            v4f vt = { lsT[l0+i], lsT[l0+i+1], lsT[l0+i+2], lsT[l0+i+3] };
            __builtin_nontemporal_store(vs, (v4f*)(outS + g0 + i));
            __builtin_nontemporal_store(vt, (v4f*)(outT + g0 + i));
        }
        if (t < tail) {
            __builtin_nontemporal_store(lsS[l0 + done + t], outS + g0 + done + t);
            __builtin_nontemporal_store(lsT[l0 + done + t], outT + g0 + done + t);
        }
    }
}

extern "C" void kernel_launch(void* const* d_in, const int* in_sizes, int n_in,
                              void* d_out, int out_size, void* d_ws, size_t ws_size,
                              hipStream_t stream) {
    const float* scores = (const float*)d_in[0];
    const int*   idx    = (const int*)d_in[1];
    const int M = in_sizes[1];                 // N_TOKENS * TOP_K flat keys

    float* out  = (float*)d_out;
    float* outS = out;                          // [0, M)   sorted scores
    float* outT = out + M;                      // [M, 2M)  token indices (as f32, exact < 2^24)
    float* outC = out + 2 * (long)M;            // [2M, 2M+8) expert counts

    const int nblocks = (M + EPB - 1) / EPB;    // 4096 for M = 16,777,216
    int* bh  = (int*)d_ws;                      // NE * nblocks ints, expert-major
    int* bhx = bh + (long)NE * nblocks;         // NE * nblocks ints, expert-major
    u32* kpk = (u32*)(bhx + (long)NE * nblocks);// packed 4-bit keys, ceil(M/8) u32

    k_hist   <<<nblocks, TPB, 0, stream>>>(idx, M, bh, nblocks, kpk);
    k_scan   <<<1, 1024, 0, stream>>>(bh, bhx, outC, nblocks, M);
    k_scatter<<<nblocks, TPB, 0, stream>>>(kpk, scores, M, bhx, nblocks, outS, outT);
}